// Round 6
// baseline (266.991 us; speedup 1.0000x reference)
//
#include <hip/hip_runtime.h>

#define NQ 5
#define DIM 32
#define WT_STRIDE 164
#define REC 80          // floats per (b,n) record: 64 state + 5 cx + 5 sx + pad
#define MAX_BN 32768    // B=4096 * NB=8

// float offsets inside scratch (d_ws or static fallback)
#define WT_OFF   0
#define PSI_OFF  2048
#define M_OFF    (PSI_OFF + MAX_BN * REC)            // 2,623,488
#define ST01_OFF (M_OFF + MAX_BN)                    // 2,656,256 (even -> float2 ok)
#define WS_FLOATS (ST01_OFF + (MAX_BN / 8) * 2 * 16 * DIM * 2)  // 11,044,864
#define WS_NEED_BYTES ((size_t)WS_FLOATS * 4)

// Static fallback scratch (used only if ws_size too small). Rewritten every
// launch before any read.
__device__ __align__(16) float g_wtab[8 * WT_STRIDE];
__device__ __align__(16) float g_psi[(size_t)MAX_BN * REC];
__device__ float g_m[MAX_BN];
__device__ float2 g_st01[(size_t)(MAX_BN / 8) * 2 * 16 * DIM];

// ---- compile-time CNOT-chain permutations -------------------------------
struct TauArr { int v[DIM]; };
constexpr TauArr make_tau(int L) {
  TauArr a{};
  for (int s = 0; s < DIM; ++s) {
    int k = s;
    for (int i = NQ - 1; i >= 0; --i) {
      int t = (i + L) % NQ;
      k ^= ((k >> (NQ - 1 - i)) & 1) << (NQ - 1 - t);
    }
    a.v[s] = k;
  }
  return a;
}
constexpr TauArr TAU1C = make_tau(1);
constexpr TauArr TAU2C = make_tau(2);

// ---- fully-unrolled in-register gate helpers ----------------------------
__device__ __forceinline__ void apply_ry(float sr[DIM], float si[DIM],
                                         const float c[NQ], const float s[NQ]) {
  #pragma unroll
  for (int q = 0; q < NQ; ++q) {
    const int m = 1 << (NQ - 1 - q);
    #pragma unroll
    for (int lo = 0; lo < DIM; ++lo) {
      if (lo & m) continue;
      const int hi = lo | m;
      float r0 = sr[lo], r1 = sr[hi];
      sr[lo] = c[q] * r0 - s[q] * r1;
      sr[hi] = s[q] * r0 + c[q] * r1;
      float i0 = si[lo], i1 = si[hi];
      si[lo] = c[q] * i0 - s[q] * i1;
      si[hi] = s[q] * i0 + c[q] * i1;
    }
  }
}

__device__ __forceinline__ void apply_rz_angles(float sr[DIM], float si[DIM],
                                                const float h[NQ]) {
  #pragma unroll
  for (int s_ = 0; s_ < DIM; ++s_) {
    float phi = ((s_ & 16) ? h[0] : -h[0]) + ((s_ & 8) ? h[1] : -h[1])
              + ((s_ & 4) ? h[2] : -h[2]) + ((s_ & 2) ? h[3] : -h[3])
              + ((s_ & 1) ? h[4] : -h[4]);
    float sp, cp;
    __sincosf(phi, &sp, &cp);
    float r = sr[s_], ii = si[s_];
    sr[s_] = r * cp - ii * sp;
    si[s_] = r * sp + ii * cp;
  }
}

// ---- kernel 0: per-n weight tables --------------------------------------
__global__ void wtabk(const float* __restrict__ w2, const float* __restrict__ w3a,
                      const float* __restrict__ w3b, const float* __restrict__ w3c,
                      float* __restrict__ ws, int use_ws) {
  int n = threadIdx.x;
  if (n >= 8) return;
  float* t = (use_ws ? ws + WT_OFF : g_wtab) + n * WT_STRIDE;
  #pragma unroll
  for (int q = 0; q < NQ; ++q) {
    float s_, c_;
    __sincosf(0.5f * w2[n * NQ + q], &s_, &c_);
    t[q] = c_; t[NQ + q] = s_;
    __sincosf(0.5f * w3b[n * NQ + q], &s_, &c_);
    t[10 + q] = c_; t[15 + q] = s_;
  }
  float ha[NQ], hc[NQ];
  #pragma unroll
  for (int q = 0; q < NQ; ++q) {
    ha[q] = 0.5f * w3a[n * NQ + q];
    hc[q] = 0.5f * w3c[n * NQ + q];
  }
  #pragma unroll
  for (int s_ = 0; s_ < DIM; ++s_) {
    float phi = ((s_ & 16) ? ha[0] : -ha[0]) + ((s_ & 8) ? ha[1] : -ha[1])
              + ((s_ & 4) ? ha[2] : -ha[2]) + ((s_ & 2) ? ha[3] : -ha[3])
              + ((s_ & 1) ? ha[4] : -ha[4]);
    float sp, cp;
    __sincosf(phi, &sp, &cp);
    t[20 + 2 * s_] = cp; t[20 + 2 * s_ + 1] = sp;
    phi = ((s_ & 16) ? hc[0] : -hc[0]) + ((s_ & 8) ? hc[1] : -hc[1])
        + ((s_ & 4) ? hc[2] : -hc[2]) + ((s_ & 2) ? hc[3] : -hc[3])
        + ((s_ & 1) ? hc[4] : -hc[4]);
    __sincosf(phi, &sp, &cp);
    t[84 + 2 * s_] = cp; t[84 + 2 * s_ + 1] = sp;
  }
}

// ---- kernel 1: phase A per (b,n) ----------------------------------------
__global__ void phaseA(const float* __restrict__ x, const float* __restrict__ w0,
                       const float* __restrict__ w1a, const float* __restrict__ w1b,
                       const float* __restrict__ w1c, float* __restrict__ ws,
                       int use_ws, int nbn) {
  int bn = blockIdx.x * blockDim.x + threadIdx.x;
  if (bn >= nbn) return;
  int b = bn >> 3, n = bn & 7;
  float cx[NQ], sx[NQ];
  #pragma unroll
  for (int q = 0; q < NQ; ++q) __sincosf(0.5f * x[b * 40 + n * NQ + q], &sx[q], &cx[q]);
  float sr[DIM], si[DIM];
  #pragma unroll
  for (int s_ = 0; s_ < DIM; ++s_) {
    sr[s_] = ((s_ & 16) ? sx[0] : cx[0]) * ((s_ & 8) ? sx[1] : cx[1])
           * ((s_ & 4) ? sx[2] : cx[2]) * ((s_ & 2) ? sx[3] : cx[3])
           * ((s_ & 1) ? sx[4] : cx[4]);
    si[s_] = 0.f;
  }
  float cw[NQ], sw[NQ], h[NQ];
  #pragma unroll
  for (int q = 0; q < NQ; ++q) __sincosf(0.5f * w0[n * NQ + q], &sw[q], &cw[q]);
  apply_ry(sr, si, cw, sw);          // RY(w0)
  apply_ry(sr, si, cx, sx);          // RY(x)
  #pragma unroll
  for (int q = 0; q < NQ; ++q) h[q] = 0.5f * w1a[n * NQ + q];
  apply_rz_angles(sr, si, h);        // RZ(w1a)
  #pragma unroll
  for (int q = 0; q < NQ; ++q) __sincosf(0.5f * w1b[n * NQ + q], &sw[q], &cw[q]);
  apply_ry(sr, si, cw, sw);          // RY(w1b)
  #pragma unroll
  for (int q = 0; q < NQ; ++q) h[q] = 0.5f * w1c[n * NQ + q];
  apply_rz_angles(sr, si, h);        // RZ(w1c)
  float tr[DIM], ti[DIM];
  #pragma unroll
  for (int s_ = 0; s_ < DIM; ++s_) { tr[s_] = sr[TAU1C.v[s_]]; ti[s_] = si[TAU1C.v[s_]]; }
  apply_ry(tr, ti, cx, sx);          // RY(x)
  float* rec = (use_ws ? ws + PSI_OFF : g_psi) + (size_t)bn * REC;
  #pragma unroll
  for (int s_ = 0; s_ < DIM; ++s_) { rec[2 * s_] = tr[s_]; rec[2 * s_ + 1] = ti[s_]; }
  #pragma unroll
  for (int q = 0; q < NQ; ++q) { rec[64 + q] = cx[q]; rec[69 + q] = sx[q]; }
}

// ---- kernel 2: phase B per (b,n,copy). MODE 0: real-only out; 1: interleaved
template <int MODE>
__global__ __launch_bounds__(256) void phaseB(float* __restrict__ outp,
                                              float* __restrict__ ws, int use_ws,
                                              int total) {
  __shared__ float lwt[8 * WT_STRIDE];
  {
    const float* wsrc = use_ws ? ws + WT_OFF : g_wtab;
    for (int i = threadIdx.x; i < 8 * WT_STRIDE; i += 256) lwt[i] = wsrc[i];
  }
  __syncthreads();
  int tid = blockIdx.x * 256 + threadIdx.x;
  if (tid >= total) return;
  int bn = tid >> 4, j = tid & 15;
  int n = bn & 7;
  const float* rec = (use_ws ? ws + PSI_OFF : g_psi) + (size_t)bn * REC;
  const float2* rec2 = (const float2*)rec;
  float sr[DIM], si[DIM];
  #pragma unroll
  for (int s_ = 0; s_ < DIM; ++s_) { float2 v = rec2[s_]; sr[s_] = v.x; si[s_] = v.y; }
  float cx[NQ], sx[NQ];
  #pragma unroll
  for (int q = 0; q < NQ; ++q) { cx[q] = rec[64 + q]; sx[q] = rec[69 + q]; }
  int xm = 0;
  if (n == 0)
    xm = ((j & 1) ? 16 : 0) | ((j & 2) ? 1 : 0) | ((j & 4) ? 8 : 0) | ((j & 8) ? 4 : 0);
  else if (n == 1)
    xm = ((j & 1) ? 16 : 0) | ((j & 2) ? 1 : 0) | ((j & 4) ? 2 : 0) | ((j & 8) ? 4 : 0);
  #pragma unroll
  for (int s_ = 0; s_ < DIM; ++s_) {
    if (__popc(s_ & xm) & 1) { sr[s_] = -sr[s_]; si[s_] = -si[s_]; }
  }
  const float* wt = lwt + n * WT_STRIDE;
  float cw[NQ], sw[NQ];
  #pragma unroll
  for (int q = 0; q < NQ; ++q) { cw[q] = wt[q]; sw[q] = wt[NQ + q]; }
  apply_ry(sr, si, cw, sw);          // RY(w2)
  apply_ry(sr, si, cx, sx);          // RY(x)
  #pragma unroll
  for (int s_ = 0; s_ < DIM; ++s_) {
    float cp = wt[20 + 2 * s_], sp = wt[20 + 2 * s_ + 1];
    float r = sr[s_], ii = si[s_];
    sr[s_] = r * cp - ii * sp; si[s_] = r * sp + ii * cp;   // RZ(w3a)
  }
  #pragma unroll
  for (int q = 0; q < NQ; ++q) { cw[q] = wt[10 + q]; sw[q] = wt[15 + q]; }
  apply_ry(sr, si, cw, sw);          // RY(w3b)
  #pragma unroll
  for (int s_ = 0; s_ < DIM; ++s_) {
    float cp = wt[84 + 2 * s_], sp = wt[84 + 2 * s_ + 1];
    float r = sr[s_], ii = si[s_];
    sr[s_] = r * cp - ii * sp; si[s_] = r * sp + ii * cp;   // RZ(w3c)
  }
  // TAU2 gather + stores + side-channel for finalO
  float2* st01 = use_ws ? (float2*)(ws + ST01_OFF) : g_st01;
  float2* st01w = st01 + ((size_t)((bn >> 3) * 2 + n) * 16 + j) * DIM;  // n<2 only
  float msum = 0.f;
  #pragma unroll
  for (int s_ = 0; s_ < DIM; ++s_) {
    int t = TAU2C.v[s_];
    float re = sr[t], im = si[t];
    float mag = re * re + im * im;
    msum += (__popc(s_) & 1) ? -mag : mag;
    if (MODE) ((float2*)outp)[(size_t)tid * DIM + s_] = make_float2(re, im);
    else      outp[(size_t)tid * DIM + s_] = re;
    if (n < 2) st01w[s_] = make_float2(re, im);
  }
  if (n >= 2 && j == 0) (use_ws ? ws + M_OFF : g_m)[bn] = msum;
}

// ---- kernel 3: O reduction, one wave per batch element ------------------
__global__ __launch_bounds__(64) void finalO(const float* __restrict__ ws, int use_ws,
                                             float* __restrict__ oout) {
  int b = blockIdx.x;
  int lane = threadIdx.x;
  const float2* st01 = use_ws ? (const float2*)(ws + ST01_OFF) : (const float2*)g_st01;
  const float* mtab = use_ws ? ws + M_OFF : g_m;
  __shared__ float2 a0[16][DIM + 1];
  __shared__ float2 a1[16][DIM + 1];
  const float2* p0 = st01 + (size_t)(b * 2 + 0) * 16 * DIM;
  const float2* p1 = st01 + (size_t)(b * 2 + 1) * 16 * DIM;
  for (int i = lane; i < 16 * DIM; i += 64) {
    a0[i >> 5][i & 31] = p0[i];
    a1[i >> 5][i & 31] = p1[i];
  }
  __syncthreads();
  float C = 1.f;
  #pragma unroll
  for (int n = 2; n < 8; ++n) C *= mtab[b * 8 + n];
  // O = C/16 * Re[ sum_{j,k} i^{(pc(j)-pc(k)) mod 4} * M0[j,k]*M1[j,k] ]
  float acc = 0.f;
  #pragma unroll
  for (int t = 0; t < 4; ++t) {
    int jk = lane + 64 * t;
    int jj = jk >> 4, kk = jk & 15;
    float m0r = 0.f, m0i = 0.f, m1r = 0.f, m1i = 0.f;
    #pragma unroll
    for (int s_ = 0; s_ < DIM; ++s_) {
      float sgn = (__popc(s_) & 1) ? -1.f : 1.f;
      float2 aj = a0[jj][s_], ak = a0[kk][s_];
      m0r += sgn * (aj.x * ak.x + aj.y * ak.y);
      m0i += sgn * (aj.x * ak.y - aj.y * ak.x);
      aj = a1[jj][s_]; ak = a1[kk][s_];
      m1r += sgn * (aj.x * ak.x + aj.y * ak.y);
      m1i += sgn * (aj.x * ak.y - aj.y * ak.x);
    }
    float zr = m0r * m1r - m0i * m1i;
    float zi = m0r * m1i + m0i * m1r;
    int d = (__popc(jj) - __popc(kk)) & 3;
    float term = (d == 0) ? zr : (d == 1) ? -zi : (d == 2) ? -zr : zi;
    acc += term;
  }
  acc *= (1.f / 16.f);
  #pragma unroll
  for (int d = 32; d >= 1; d >>= 1) acc += __shfl_xor(acc, d);
  if (lane == 0) oout[b] = C * acc;
}

extern "C" void kernel_launch(void* const* d_in, const int* in_sizes, int n_in,
                              void* d_out, int out_size, void* d_ws, size_t ws_size,
                              hipStream_t stream) {
  const float* x   = (const float*)d_in[0];
  const float* w0  = (const float*)d_in[1];
  const float* w1a = (const float*)d_in[2];
  const float* w1b = (const float*)d_in[3];
  const float* w1c = (const float*)d_in[4];
  const float* w2  = (const float*)d_in[5];
  const float* w3a = (const float*)d_in[6];
  const float* w3b = (const float*)d_in[7];
  const float* w3c = (const float*)d_in[8];
  float* out = (float*)d_out;
  float* ws  = (float*)d_ws;
  int use_ws = (ws_size >= WS_NEED_BYTES) ? 1 : 0;

  int B = in_sizes[0] / 40;          // 4096
  int nbn = B * 8;                   // (b,n) pairs (<= MAX_BN)
  int total = nbn * 16;              // (b,n,copy) triples
  // Output layout: interleaved complex (2 floats/amp) vs real-part-only.
  long long interleaved_sz = (long long)total * DIM * 2;
  int interleaved = ((long long)out_size >= interleaved_sz) ? 1 : 0;
  float* oout = out + (interleaved ? (size_t)total * DIM * 2 : (size_t)total * DIM);

  wtabk<<<1, 64, 0, stream>>>(w2, w3a, w3b, w3c, ws, use_ws);
  phaseA<<<(nbn + 255) / 256, 256, 0, stream>>>(x, w0, w1a, w1b, w1c, ws, use_ws, nbn);
  if (interleaved)
    phaseB<1><<<(total + 255) / 256, 256, 0, stream>>>(out, ws, use_ws, total);
  else
    phaseB<0><<<(total + 255) / 256, 256, 0, stream>>>(out, ws, use_ws, total);
  finalO<<<B, 64, 0, stream>>>(ws, use_ws, oout);
}

// Round 16
// 202.957 us; speedup vs baseline: 1.3155x; 1.3155x over previous
//
#include <hip/hip_runtime.h>

#define NQ 5
#define DIM 32
#define WT_STRIDE 164
#define REC 80          // floats per (b,n) record: 64 state + 5 cx + 5 sx + pad
#define MAX_BN 32768    // B=4096 * NB=8

// float offsets inside scratch (d_ws or static fallback)
#define WT_OFF   0
#define PSI_OFF  2048
#define M_OFF    (PSI_OFF + MAX_BN * REC)            // 2,623,488
#define ST01_OFF (M_OFF + MAX_BN)                    // 2,656,256 (16B-aligned)
#define WS_FLOATS (ST01_OFF + (MAX_BN / 8) * 2 * 16 * DIM * 2)  // 11,044,864
#define WS_NEED_BYTES ((size_t)WS_FLOATS * 4)

// Static fallback scratch (used only if ws_size too small). Rewritten every
// launch before any read.
__device__ __align__(16) float g_wtab[8 * WT_STRIDE];
__device__ __align__(16) float g_psi[(size_t)MAX_BN * REC];
__device__ float g_m[MAX_BN];
__device__ __align__(16) float2 g_st01[(size_t)(MAX_BN / 8) * 2 * 16 * DIM];

// ---- compile-time CNOT-chain permutations -------------------------------
struct TauArr { int v[DIM]; };
constexpr TauArr make_tau(int L) {
  TauArr a{};
  for (int s = 0; s < DIM; ++s) {
    int k = s;
    for (int i = NQ - 1; i >= 0; --i) {
      int t = (i + L) % NQ;
      k ^= ((k >> (NQ - 1 - i)) & 1) << (NQ - 1 - t);
    }
    a.v[s] = k;
  }
  return a;
}
constexpr TauArr TAU1C = make_tau(1);
constexpr TauArr TAU2C = make_tau(2);

// ---- fully-unrolled in-register gate helpers ----------------------------
__device__ __forceinline__ void apply_ry(float sr[DIM], float si[DIM],
                                         const float c[NQ], const float s[NQ]) {
  #pragma unroll
  for (int q = 0; q < NQ; ++q) {
    const int m = 1 << (NQ - 1 - q);
    #pragma unroll
    for (int lo = 0; lo < DIM; ++lo) {
      if (lo & m) continue;
      const int hi = lo | m;
      float r0 = sr[lo], r1 = sr[hi];
      sr[lo] = c[q] * r0 - s[q] * r1;
      sr[hi] = s[q] * r0 + c[q] * r1;
      float i0 = si[lo], i1 = si[hi];
      si[lo] = c[q] * i0 - s[q] * i1;
      si[hi] = s[q] * i0 + c[q] * i1;
    }
  }
}

__device__ __forceinline__ void apply_rz_angles(float sr[DIM], float si[DIM],
                                                const float h[NQ]) {
  #pragma unroll
  for (int s_ = 0; s_ < DIM; ++s_) {
    float phi = ((s_ & 16) ? h[0] : -h[0]) + ((s_ & 8) ? h[1] : -h[1])
              + ((s_ & 4) ? h[2] : -h[2]) + ((s_ & 2) ? h[3] : -h[3])
              + ((s_ & 1) ? h[4] : -h[4]);
    float sp, cp;
    __sincosf(phi, &sp, &cp);
    float r = sr[s_], ii = si[s_];
    sr[s_] = r * cp - ii * sp;
    si[s_] = r * sp + ii * cp;
  }
}

// ---- kernel 0: per-n weight tables --------------------------------------
__global__ void wtabk(const float* __restrict__ w2, const float* __restrict__ w3a,
                      const float* __restrict__ w3b, const float* __restrict__ w3c,
                      float* __restrict__ ws, int use_ws) {
  int n = threadIdx.x;
  if (n >= 8) return;
  float* t = (use_ws ? ws + WT_OFF : g_wtab) + n * WT_STRIDE;
  #pragma unroll
  for (int q = 0; q < NQ; ++q) {
    float s_, c_;
    __sincosf(0.5f * w2[n * NQ + q], &s_, &c_);
    t[q] = c_; t[NQ + q] = s_;
    __sincosf(0.5f * w3b[n * NQ + q], &s_, &c_);
    t[10 + q] = c_; t[15 + q] = s_;
  }
  float ha[NQ], hc[NQ];
  #pragma unroll
  for (int q = 0; q < NQ; ++q) {
    ha[q] = 0.5f * w3a[n * NQ + q];
    hc[q] = 0.5f * w3c[n * NQ + q];
  }
  #pragma unroll
  for (int s_ = 0; s_ < DIM; ++s_) {
    float phi = ((s_ & 16) ? ha[0] : -ha[0]) + ((s_ & 8) ? ha[1] : -ha[1])
              + ((s_ & 4) ? ha[2] : -ha[2]) + ((s_ & 2) ? ha[3] : -ha[3])
              + ((s_ & 1) ? ha[4] : -ha[4]);
    float sp, cp;
    __sincosf(phi, &sp, &cp);
    t[20 + 2 * s_] = cp; t[20 + 2 * s_ + 1] = sp;
    phi = ((s_ & 16) ? hc[0] : -hc[0]) + ((s_ & 8) ? hc[1] : -hc[1])
        + ((s_ & 4) ? hc[2] : -hc[2]) + ((s_ & 2) ? hc[3] : -hc[3])
        + ((s_ & 1) ? hc[4] : -hc[4]);
    __sincosf(phi, &sp, &cp);
    t[84 + 2 * s_] = cp; t[84 + 2 * s_ + 1] = sp;
  }
}

// ---- kernel 1: phase A per (b,n) ----------------------------------------
__global__ void phaseA(const float* __restrict__ x, const float* __restrict__ w0,
                       const float* __restrict__ w1a, const float* __restrict__ w1b,
                       const float* __restrict__ w1c, float* __restrict__ ws,
                       int use_ws, int nbn) {
  int bn = blockIdx.x * blockDim.x + threadIdx.x;
  if (bn >= nbn) return;
  int b = bn >> 3, n = bn & 7;
  float cx[NQ], sx[NQ];
  #pragma unroll
  for (int q = 0; q < NQ; ++q) __sincosf(0.5f * x[b * 40 + n * NQ + q], &sx[q], &cx[q]);
  float sr[DIM], si[DIM];
  #pragma unroll
  for (int s_ = 0; s_ < DIM; ++s_) {
    sr[s_] = ((s_ & 16) ? sx[0] : cx[0]) * ((s_ & 8) ? sx[1] : cx[1])
           * ((s_ & 4) ? sx[2] : cx[2]) * ((s_ & 2) ? sx[3] : cx[3])
           * ((s_ & 1) ? sx[4] : cx[4]);
    si[s_] = 0.f;
  }
  float cw[NQ], sw[NQ], h[NQ];
  #pragma unroll
  for (int q = 0; q < NQ; ++q) __sincosf(0.5f * w0[n * NQ + q], &sw[q], &cw[q]);
  apply_ry(sr, si, cw, sw);          // RY(w0)
  apply_ry(sr, si, cx, sx);          // RY(x)
  #pragma unroll
  for (int q = 0; q < NQ; ++q) h[q] = 0.5f * w1a[n * NQ + q];
  apply_rz_angles(sr, si, h);        // RZ(w1a)
  #pragma unroll
  for (int q = 0; q < NQ; ++q) __sincosf(0.5f * w1b[n * NQ + q], &sw[q], &cw[q]);
  apply_ry(sr, si, cw, sw);          // RY(w1b)
  #pragma unroll
  for (int q = 0; q < NQ; ++q) h[q] = 0.5f * w1c[n * NQ + q];
  apply_rz_angles(sr, si, h);        // RZ(w1c)
  float tr[DIM], ti[DIM];
  #pragma unroll
  for (int s_ = 0; s_ < DIM; ++s_) { tr[s_] = sr[TAU1C.v[s_]]; ti[s_] = si[TAU1C.v[s_]]; }
  apply_ry(tr, ti, cx, sx);          // RY(x)
  float* rec = (use_ws ? ws + PSI_OFF : g_psi) + (size_t)bn * REC;
  // vectorized record store: state as 16 float4, then cx/sx
  #pragma unroll
  for (int s4 = 0; s4 < 16; ++s4)
    *(float4*)&rec[4 * s4] = make_float4(tr[2 * s4], ti[2 * s4], tr[2 * s4 + 1], ti[2 * s4 + 1]);
  *(float4*)&rec[64] = make_float4(cx[0], cx[1], cx[2], cx[3]);
  *(float4*)&rec[68] = make_float4(cx[4], sx[0], sx[1], sx[2]);
  *(float2*)&rec[72] = make_float2(sx[3], sx[4]);
}

// ---- kernel 2: phase B per (b,n,copy). MODE 0: real-only out; 1: interleaved
template <int MODE>
__global__ __launch_bounds__(256) void phaseB(float* __restrict__ outp,
                                              float* __restrict__ ws, int use_ws,
                                              int total) {
  __shared__ float lwt[8 * WT_STRIDE];
  {
    const float* wsrc = use_ws ? ws + WT_OFF : g_wtab;
    for (int i = threadIdx.x; i < 8 * WT_STRIDE; i += 256) lwt[i] = wsrc[i];
  }
  __syncthreads();
  int tid = blockIdx.x * 256 + threadIdx.x;
  if (tid >= total) return;
  int bn = tid >> 4, j = tid & 15;
  int n = bn & 7;
  const float* rec = (use_ws ? ws + PSI_OFF : g_psi) + (size_t)bn * REC;
  const float4* rec4 = (const float4*)rec;
  float sr[DIM], si[DIM];
  #pragma unroll
  for (int s4 = 0; s4 < 16; ++s4) {
    float4 v = rec4[s4];
    sr[2 * s4] = v.x; si[2 * s4] = v.y; sr[2 * s4 + 1] = v.z; si[2 * s4 + 1] = v.w;
  }
  float cx[NQ], sx[NQ];
  {
    float4 c0 = rec4[16], c1 = rec4[17];
    float2 c2 = *(const float2*)&rec[72];
    cx[0] = c0.x; cx[1] = c0.y; cx[2] = c0.z; cx[3] = c0.w;
    cx[4] = c1.x; sx[0] = c1.y; sx[1] = c1.z; sx[2] = c1.w;
    sx[3] = c2.x; sx[4] = c2.y;
  }
  int xm = 0;
  if (n == 0)
    xm = ((j & 1) ? 16 : 0) | ((j & 2) ? 1 : 0) | ((j & 4) ? 8 : 0) | ((j & 8) ? 4 : 0);
  else if (n == 1)
    xm = ((j & 1) ? 16 : 0) | ((j & 2) ? 1 : 0) | ((j & 4) ? 2 : 0) | ((j & 8) ? 4 : 0);
  #pragma unroll
  for (int s_ = 0; s_ < DIM; ++s_) {
    if (__popc(s_ & xm) & 1) { sr[s_] = -sr[s_]; si[s_] = -si[s_]; }
  }
  const float* wt = lwt + n * WT_STRIDE;
  float cw[NQ], sw[NQ];
  #pragma unroll
  for (int q = 0; q < NQ; ++q) { cw[q] = wt[q]; sw[q] = wt[NQ + q]; }
  apply_ry(sr, si, cw, sw);          // RY(w2)
  apply_ry(sr, si, cx, sx);          // RY(x)
  #pragma unroll
  for (int s_ = 0; s_ < DIM; ++s_) {
    float cp = wt[20 + 2 * s_], sp = wt[20 + 2 * s_ + 1];
    float r = sr[s_], ii = si[s_];
    sr[s_] = r * cp - ii * sp; si[s_] = r * sp + ii * cp;   // RZ(w3a)
  }
  #pragma unroll
  for (int q = 0; q < NQ; ++q) { cw[q] = wt[10 + q]; sw[q] = wt[15 + q]; }
  apply_ry(sr, si, cw, sw);          // RY(w3b)
  #pragma unroll
  for (int s_ = 0; s_ < DIM; ++s_) {
    float cp = wt[84 + 2 * s_], sp = wt[84 + 2 * s_ + 1];
    float r = sr[s_], ii = si[s_];
    sr[s_] = r * cp - ii * sp; si[s_] = r * sp + ii * cp;   // RZ(w3c)
  }
  // TAU2 gather into ordered registers
  float orr[DIM], oii[DIM];
  #pragma unroll
  for (int s_ = 0; s_ < DIM; ++s_) {
    int t = TAU2C.v[s_];
    orr[s_] = sr[t]; oii[s_] = si[t];
  }
  // vectorized output stores (16B per lane per instruction)
  if (MODE) {
    float2* o2 = (float2*)outp + (size_t)tid * DIM;
    #pragma unroll
    for (int s2 = 0; s2 < DIM / 2; ++s2)
      *(float4*)&o2[2 * s2] = make_float4(orr[2 * s2], oii[2 * s2],
                                          orr[2 * s2 + 1], oii[2 * s2 + 1]);
  } else {
    float* o = outp + (size_t)tid * DIM;
    #pragma unroll
    for (int s4 = 0; s4 < DIM / 4; ++s4)
      *(float4*)&o[4 * s4] = make_float4(orr[4 * s4], orr[4 * s4 + 1],
                                         orr[4 * s4 + 2], orr[4 * s4 + 3]);
  }
  if (n < 2) {
    float2* st01 = use_ws ? (float2*)(ws + ST01_OFF) : g_st01;
    float2* w2p = st01 + ((size_t)((bn >> 3) * 2 + n) * 16 + j) * DIM;
    #pragma unroll
    for (int s2 = 0; s2 < DIM / 2; ++s2)
      *(float4*)&w2p[2 * s2] = make_float4(orr[2 * s2], oii[2 * s2],
                                           orr[2 * s2 + 1], oii[2 * s2 + 1]);
  } else if (j == 0) {
    float msum = 0.f;
    #pragma unroll
    for (int s_ = 0; s_ < DIM; ++s_) {
      float mag = orr[s_] * orr[s_] + oii[s_] * oii[s_];
      msum += (__popc(s_) & 1) ? -mag : mag;
    }
    (use_ws ? ws + M_OFF : g_m)[bn] = msum;
  }
}

// ---- kernel 3: O reduction, one wave per batch element ------------------
__global__ __launch_bounds__(64) void finalO(const float* __restrict__ ws, int use_ws,
                                             float* __restrict__ oout) {
  int b = blockIdx.x;
  int lane = threadIdx.x;
  const float2* st01 = use_ws ? (const float2*)(ws + ST01_OFF) : (const float2*)g_st01;
  const float* mtab = use_ws ? ws + M_OFF : g_m;
  __shared__ float2 a0[16][DIM + 1];
  __shared__ float2 a1[16][DIM + 1];
  const float2* p0 = st01 + (size_t)(b * 2 + 0) * 16 * DIM;
  const float2* p1 = st01 + (size_t)(b * 2 + 1) * 16 * DIM;
  for (int i = lane; i < 16 * DIM; i += 64) {
    a0[i >> 5][i & 31] = p0[i];
    a1[i >> 5][i & 31] = p1[i];
  }
  __syncthreads();
  float C = 1.f;
  #pragma unroll
  for (int n = 2; n < 8; ++n) C *= mtab[b * 8 + n];
  // O = C/16 * Re[ sum_{j,k} i^{(pc(j)-pc(k)) mod 4} * M0[j,k]*M1[j,k] ]
  float acc = 0.f;
  #pragma unroll
  for (int t = 0; t < 4; ++t) {
    int jk = lane + 64 * t;
    int jj = jk >> 4, kk = jk & 15;
    float m0r = 0.f, m0i = 0.f, m1r = 0.f, m1i = 0.f;
    #pragma unroll
    for (int s_ = 0; s_ < DIM; ++s_) {
      float sgn = (__popc(s_) & 1) ? -1.f : 1.f;
      float2 aj = a0[jj][s_], ak = a0[kk][s_];
      m0r += sgn * (aj.x * ak.x + aj.y * ak.y);
      m0i += sgn * (aj.x * ak.y - aj.y * ak.x);
      aj = a1[jj][s_]; ak = a1[kk][s_];
      m1r += sgn * (aj.x * ak.x + aj.y * ak.y);
      m1i += sgn * (aj.x * ak.y - aj.y * ak.x);
    }
    float zr = m0r * m1r - m0i * m1i;
    float zi = m0r * m1i + m0i * m1r;
    int d = (__popc(jj) - __popc(kk)) & 3;
    float term = (d == 0) ? zr : (d == 1) ? -zi : (d == 2) ? -zr : zi;
    acc += term;
  }
  acc *= (1.f / 16.f);
  #pragma unroll
  for (int d = 32; d >= 1; d >>= 1) acc += __shfl_xor(acc, d);
  if (lane == 0) oout[b] = C * acc;
}

extern "C" void kernel_launch(void* const* d_in, const int* in_sizes, int n_in,
                              void* d_out, int out_size, void* d_ws, size_t ws_size,
                              hipStream_t stream) {
  const float* x   = (const float*)d_in[0];
  const float* w0  = (const float*)d_in[1];
  const float* w1a = (const float*)d_in[2];
  const float* w1b = (const float*)d_in[3];
  const float* w1c = (const float*)d_in[4];
  const float* w2  = (const float*)d_in[5];
  const float* w3a = (const float*)d_in[6];
  const float* w3b = (const float*)d_in[7];
  const float* w3c = (const float*)d_in[8];
  float* out = (float*)d_out;
  float* ws  = (float*)d_ws;
  int use_ws = (ws_size >= WS_NEED_BYTES) ? 1 : 0;

  int B = in_sizes[0] / 40;          // 4096
  int nbn = B * 8;                   // (b,n) pairs (<= MAX_BN)
  int total = nbn * 16;              // (b,n,copy) triples
  // Output layout: interleaved complex (2 floats/amp) vs real-part-only.
  long long interleaved_sz = (long long)total * DIM * 2;
  int interleaved = ((long long)out_size >= interleaved_sz) ? 1 : 0;
  float* oout = out + (interleaved ? (size_t)total * DIM * 2 : (size_t)total * DIM);

  wtabk<<<1, 64, 0, stream>>>(w2, w3a, w3b, w3c, ws, use_ws);
  phaseA<<<(nbn + 255) / 256, 256, 0, stream>>>(x, w0, w1a, w1b, w1c, ws, use_ws, nbn);
  if (interleaved)
    phaseB<1><<<(total + 255) / 256, 256, 0, stream>>>(out, ws, use_ws, total);
  else
    phaseB<0><<<(total + 255) / 256, 256, 0, stream>>>(out, ws, use_ws, total);
  finalO<<<B, 64, 0, stream>>>(ws, use_ws, oout);
}